// Round 10
// baseline (892.845 us; speedup 1.0000x reference)
//
#include <hip/hip_runtime.h>
#include <math.h>

// Problem constants
#define BB      128
#define NNODES  1023
#define HD      256
#define LEAVES  512
#define IOU3    768     // 3*H
#define CAT2    512     // 2*H
#define LDCOMB  1280    // f(512) + iou(768)

typedef unsigned short ushort_t;
typedef __bf16 bf16x8 __attribute__((ext_vector_type(8)));
typedef float  f32x4  __attribute__((ext_vector_type(4)));
typedef float  f32x16 __attribute__((ext_vector_type(16)));

__device__ __forceinline__ float sigf(float x) { return 1.0f / (1.0f + expf(-x)); }

// async global->LDS DMA, 16B per lane, linear dest (base + lane*16)
__device__ __forceinline__ void gload16(const void* g, void* l)
{
    __builtin_amdgcn_global_load_lds(
        (const __attribute__((address_space(1))) unsigned int*)g,
        (__attribute__((address_space(3))) unsigned int*)l, 16, 0, 0);
}

// split fp32 -> bf16 hi + bf16 lo (round-to-nearest-even, bit ops)
__device__ __forceinline__ void split_bf16(float x, ushort_t& h, ushort_t& l)
{
    unsigned u = __float_as_uint(x);
    unsigned r = u + 0x7fff + ((u >> 16) & 1);
    h = (ushort_t)(r >> 16);
    float fh = __uint_as_float((unsigned)h << 16);
    float d = x - fh;
    unsigned u2 = __float_as_uint(d);
    unsigned r2 = u2 + 0x7fff + ((u2 >> 16) & 1);
    l = (ushort_t)(r2 >> 16);
}

__device__ __forceinline__ float rh2(ushort_t h, ushort_t l)
{
    return __uint_as_float((unsigned)h << 16) + __uint_as_float((unsigned)l << 16);
}

// ---------------------------------------------------------------------------
// generic fp32 array -> hi/lo bf16 arrays (4 elements/thread)
// ---------------------------------------------------------------------------
__global__ void k_split4(const float* __restrict__ src, ushort_t* __restrict__ hi,
                         ushort_t* __restrict__ lo, int n4)
{
    int i = blockIdx.x * 256 + threadIdx.x;
    if (i >= n4) return;
    float4 v = ((const float4*)src)[i];
    ushort4 hv, lv;
    split_bf16(v.x, hv.x, lv.x);
    split_bf16(v.y, hv.y, lv.y);
    split_bf16(v.z, hv.z, lv.z);
    split_bf16(v.w, hv.w, lv.w);
    ((ushort4*)hi)[i] = hv;
    ((ushort4*)lo)[i] = lv;
}

// build Wcat = [Uf_W(512 rows) ; U_iou(768 rows)], K=512, as hi/lo bf16
__global__ void k_build_wcat(const float* __restrict__ Uf, const float* __restrict__ Ui,
                             ushort_t* __restrict__ hi, ushort_t* __restrict__ lo)
{
    int i = blockIdx.x * 256 + threadIdx.x;       // over 1280*128 float4s
    if (i >= 1280 * 128) return;
    int row = i >> 7, c4 = i & 127;
    const float* src = (row < 512) ? (Uf + (size_t)row * 512)
                                   : (Ui + (size_t)(row - 512) * 512);
    float4 v = ((const float4*)src)[c4];
    ushort4 hv, lv;
    split_bf16(v.x, hv.x, lv.x);
    split_bf16(v.y, hv.y, lv.y);
    split_bf16(v.z, hv.z, lv.z);
    split_bf16(v.w, hv.w, lv.w);
    ((ushort4*)hi)[i] = hv;
    ((ushort4*)lo)[i] = lv;
}

// ---------------------------------------------------------------------------
// MFMA split-bf16 GEMM:  C[m][n] = sum_k A[m][k]*W[n][k]  (fp32-accurate)
// Block 128x128, BK=16, 256 threads = 4 waves (2m x 2n), wave tile 64x64
// of 2x2 mfma_f32_32x32x16_bf16 frags (12 MFMA/K-step). 16KB buffers,
// dbuf 32KB -> 4 blocks/CU = 16 waves/CU. Counted vmcnt(4) pipeline.
// LDS swizzle (round-9 conflict fix): 16B-slot index s = 2*row + khalf is
// placed at s' = s ^ ((row>>2)&7). Every 8 consecutive lanes of a
// ds_read_b128 then covers all 8 bank groups exactly once -> conflict-free.
// DMA dest stays LINEAR (slot = tid); the inverse permutation is applied to
// the per-thread GLOBAL source (rule #21 both-sides-or-neither).
// Slab swizzle keeps per-XCD set < 4MB L2 (rounds 3/6 lesson).
// ---------------------------------------------------------------------------
#define BM 128
#define BN 128
#define BK 16

__global__ __launch_bounds__(256, 4)
void gemm_mfma(const ushort_t* __restrict__ Ahi, const ushort_t* __restrict__ Alo,
               const int* __restrict__ ids,
               int lognpar, unsigned sB, int sP, int m0, int K,
               const ushort_t* __restrict__ Bhi, const ushort_t* __restrict__ Blo,
               float* __restrict__ C, int ldc)
{
    __shared__ __align__(16) char lds[32768];
    const int tid = threadIdx.x;

    // slab-ordered, XCD-preserving block swizzle
    int bx = blockIdx.x, by = blockIdx.y;
    {
        const int gx = gridDim.x, gy = gridDim.y;
        if ((gx & 7) == 0) {
            int f = by * gx + bx;        // HW dispatch order (x fastest)
            int span = gy << 3;          // 8 * gy blocks per slab
            int s = f / span;
            int wv = f - s * span;
            bx = (s << 3) + (wv & 7);    // bx % 8 == f % 8 -> same XCD
            by = wv >> 3;
        }
    }

    const int w = tid >> 6, lane = tid & 63;

    // ---- DMA staging: thread t owns PHYS slot t (16B) of each component.
    // logical (row, khalf): x = (t&7) ^ ((t>>3)&7); row = 4*(t>>3) + (x>>1);
    // khalf = x&1.  (inverse of s' = s ^ ((row>>2)&7))
    unsigned aoff, boff;
    {
        int x = (tid & 7) ^ ((tid >> 3) & 7);
        int row = ((tid >> 3) << 2) | (x >> 1);
        int hlog = x & 1;
        int mg = m0 + bx * BM + row;
        unsigned ab;
        if (ids) {
            ab = (unsigned)ids[mg] * (unsigned)K;
        } else {
            int b = mg >> lognpar;
            int q = mg & ((1 << lognpar) - 1);
            ab = (unsigned)b * sB + (unsigned)q * (unsigned)sP;
        }
        aoff = ab + hlog * 8;
        boff = (unsigned)(by * BN + row) * (unsigned)K + hlog * 8;
    }
    const int wdst = w * 1024;                     // wave-uniform dest offset

    auto STAGE = [&](int k0, char* buf) {
        gload16(Ahi + aoff + k0, buf +     0 + wdst);
        gload16(Alo + aoff + k0, buf +  4096 + wdst);
        gload16(Bhi + boff + k0, buf +  8192 + wdst);
        gload16(Blo + boff + k0, buf + 12288 + wdst);
    };

    // fragment read addrs: 4 waves 2(m) x 2(n); wave 64x64 of 32x32 frags.
    // lane: row = base + (lane&31), khalf = lane>>5;
    // byte = ((2*row + khalf) ^ ((row>>2)&7)) * 16 ; +1024 per +32 rows.
    const int wm = w >> 1, wn = w & 1;
    const int frow = lane & 31, fh = lane >> 5;
    const int arow0 = wm * 64 + frow;
    const int brow0 = wn * 64 + frow;
    const int rdA = ((2 * arow0 + fh) ^ ((arow0 >> 2) & 7)) << 4;
    const int rdB = ((2 * brow0 + fh) ^ ((brow0 >> 2) & 7)) << 4;

    f32x16 acc[2][2];
#pragma unroll
    for (int mi = 0; mi < 2; ++mi)
#pragma unroll
        for (int ni = 0; ni < 2; ++ni)
#pragma unroll
            for (int r = 0; r < 16; ++r) acc[mi][ni][r] = 0.f;

    const int nt = K / BK;
    STAGE(0, lds);
    int cur = 0;
    for (int t = 0; t < nt; ++t) {
        if (t + 1 < nt) {
            STAGE((t + 1) * BK, lds + (cur ^ 1) * 16384);
            asm volatile("s_waitcnt vmcnt(4)" ::: "memory");   // stage-t landed
        } else {
            asm volatile("s_waitcnt vmcnt(0)" ::: "memory");   // final drain
        }
        __builtin_amdgcn_s_barrier();          // all waves: buf[cur] ready
        __builtin_amdgcn_sched_barrier(0);
        char* base = lds + cur * 16384;
        bf16x8 ah[2], al[2], bh[2], bl[2];
#pragma unroll
        for (int f = 0; f < 2; ++f) {
            ah[f] = *(const bf16x8*)(base +         rdA + f * 1024);
            al[f] = *(const bf16x8*)(base +  4096 + rdA + f * 1024);
            bh[f] = *(const bf16x8*)(base +  8192 + rdB + f * 1024);
            bl[f] = *(const bf16x8*)(base + 12288 + rdB + f * 1024);
        }
        __builtin_amdgcn_s_setprio(1);
#pragma unroll
        for (int mi = 0; mi < 2; ++mi)
#pragma unroll
            for (int ni = 0; ni < 2; ++ni) {
                acc[mi][ni] = __builtin_amdgcn_mfma_f32_32x32x16_bf16(ah[mi], bh[ni], acc[mi][ni], 0, 0, 0);
                acc[mi][ni] = __builtin_amdgcn_mfma_f32_32x32x16_bf16(ah[mi], bl[ni], acc[mi][ni], 0, 0, 0);
                acc[mi][ni] = __builtin_amdgcn_mfma_f32_32x32x16_bf16(al[mi], bh[ni], acc[mi][ni], 0, 0, 0);
            }
        __builtin_amdgcn_s_setprio(0);
        __builtin_amdgcn_s_barrier();          // reads of buf[cur] done
        cur ^= 1;
    }

    // ---- epilogue: per-wave repack through LDS -> 256B-contiguous stores ----
    // C/D layout (m74/m101): col = lane&31, row = (r&3) + 8*(r>>2) + 4*(lane>>5).
    {
        char* patch = lds + w * 4352;
        const int cl = lane & 15, rg = lane >> 4;
        const int gcol0 = by * BN + wn * 64;
        const int prow4 = 4 * fh;                  // 4*(lane>>5)
#pragma unroll
        for (int mi = 0; mi < 2; ++mi) {
#pragma unroll
            for (int hf = 0; hf < 2; ++hf) {
#pragma unroll
                for (int ni = 0; ni < 2; ++ni)
#pragma unroll
                    for (int rr = 0; rr < 8; ++rr) {
                        int r = hf * 8 + rr;
                        int prow = (rr & 3) + 8 * ((rr >> 2) & 1) + prow4;
                        *(float*)(patch + prow * 272 + (ni * 32 + frow) * 4) = acc[mi][ni][r];
                    }
                int grow0 = bx * BM + wm * 64 + mi * 32 + hf * 16;
#pragma unroll
                for (int it = 0; it < 4; ++it) {
                    int lr = it * 4 + rg;
                    f32x4 vv = *(const f32x4*)(patch + lr * 272 + cl * 16);
                    *(f32x4*)(C + (size_t)(grow0 + lr) * ldc + gcol0 + cl * 4) = vv;
                }
            }
        }
    }
}

// ---------------------------------------------------------------------------
// leaf id gather
// ---------------------------------------------------------------------------
__global__ void k_leaf_ids(const int* __restrict__ wordid, int* __restrict__ ids)
{
    int idx = blockIdx.x * 256 + threadIdx.x;   // 65536 total
    int b = idx >> 9, leaf = idx & 511;
    ids[idx] = wordid[b * NNODES + 511 + leaf];
}

// ---------------------------------------------------------------------------
// leaf apply: buf[m][768] (iou) -> h(hi/lo), c at node 511+leaf
// ---------------------------------------------------------------------------
__global__ void k_apply_leaf(const float* __restrict__ buf, const float* __restrict__ b_iou,
                             const float* __restrict__ c0,
                             ushort_t* __restrict__ hhi, ushort_t* __restrict__ hlo,
                             float* __restrict__ c, int m0)
{
    int idx = blockIdx.x * 256 + threadIdx.x;
    int m_l = idx >> 8, hh = idx & 255;
    int mg = m0 + m_l;
    int b = mg >> 9, leaf = mg & 511;
    int node = 511 + leaf;
    const float* br = buf + (size_t)m_l * IOU3;
    float iv = br[hh]        + b_iou[hh];
    float ov = br[256 + hh]  + b_iou[256 + hh];
    float uv = br[512 + hh]  + b_iou[512 + hh];
    size_t nb = ((size_t)b * NNODES + node) * HD + hh;
    float cn = sigf(iv) * tanhf(uv) + c0[nb];
    float hn = sigf(ov) * tanhf(cn);
    c[nb] = cn;
    split_bf16(hn, hhi[nb], hlo[nb]);
}

// ---------------------------------------------------------------------------
// level apply: buf[m][1280] = [f_l | f_r | i | o | u]
// ---------------------------------------------------------------------------
__global__ void k_apply_level(const float* __restrict__ buf, const float* __restrict__ b_iou,
                              const float* __restrict__ Uf_b,
                              ushort_t* __restrict__ hhi, ushort_t* __restrict__ hlo,
                              float* __restrict__ c,
                              int m0, int lognpar, int ps, int cs)
{
    int idx = blockIdx.x * 256 + threadIdx.x;
    int m_l = idx >> 8, hh = idx & 255;
    int mg = m0 + m_l;
    int b = mg >> lognpar;
    int p = mg & ((1 << lognpar) - 1);
    const float* br = buf + (size_t)m_l * LDCOMB;
    float fl = sigf(br[hh]        + Uf_b[hh]);
    float fr = sigf(br[256 + hh]  + Uf_b[256 + hh]);
    size_t cb = ((size_t)b * NNODES + cs + 2 * p) * HD + hh;
    float csum = fl * c[cb] + fr * c[cb + HD];
    float iv = br[512 + hh]  + b_iou[hh];
    float ov = br[768 + hh]  + b_iou[256 + hh];
    float uv = br[1024 + hh] + b_iou[512 + hh];
    float cn = sigf(iv) * tanhf(uv) + csum;
    float hn = sigf(ov) * tanhf(cn);
    size_t pb = ((size_t)b * NNODES + ps + p) * HD + hh;
    c[pb] = cn;
    split_bf16(hn, hhi[pb], hlo[pb]);
}

// ---------------------------------------------------------------------------
// v[b][k] = sum_g h[b][0][g] * Wmem[g][k]
// ---------------------------------------------------------------------------
__global__ void k_dec_v(const ushort_t* __restrict__ hhi, const ushort_t* __restrict__ hlo,
                        const float* __restrict__ Wmem, float* __restrict__ v)
{
    int b = blockIdx.x, k = threadIdx.x;
    __shared__ float dec[HD];
    size_t base = (size_t)b * NNODES * HD;
    dec[k] = rh2(hhi[base + k], hlo[base + k]);
    __syncthreads();
    float s = 0.f;
    for (int g = 0; g < HD; ++g) s = fmaf(dec[g], Wmem[g * HD + k], s);
    v[b * HD + k] = s;
}

// ---------------------------------------------------------------------------
// scores[b][n] = v_b . h[b][n]
// ---------------------------------------------------------------------------
__global__ void k_scores(const ushort_t* __restrict__ hhi, const ushort_t* __restrict__ hlo,
                         const float* __restrict__ v, float* __restrict__ scores)
{
    int b = blockIdx.x;
    int w = threadIdx.x >> 6, lane = threadIdx.x & 63;
    int n = blockIdx.y * 4 + w;
    if (n >= NNODES) return;
    size_t hb = ((size_t)b * NNODES + n) * HD;
    ushort4 ph = *(const ushort4*)(hhi + hb + lane * 4);
    ushort4 pl = *(const ushort4*)(hlo + hb + lane * 4);
    float4 vv = *(const float4*)(v + b * HD + lane * 4);
    float s = rh2(ph.x, pl.x) * vv.x + rh2(ph.y, pl.y) * vv.y +
              rh2(ph.z, pl.z) * vv.z + rh2(ph.w, pl.w) * vv.w;
#pragma unroll
    for (int o = 32; o; o >>= 1) s += __shfl_down(s, o);
    if (lane == 0) scores[(size_t)b * NNODES + n] = s;
}

// ---------------------------------------------------------------------------
// softmax over n (1023) per batch row
// ---------------------------------------------------------------------------
__global__ void k_softmax(const float* __restrict__ scores, float* __restrict__ attn)
{
    int b = blockIdx.x, t = threadIdx.x;
    __shared__ float red[4];
    float sv[4];
    float m = -INFINITY;
#pragma unroll
    for (int i = 0; i < 4; ++i) {
        int n = t + 256 * i;
        sv[i] = (n < NNODES) ? scores[(size_t)b * NNODES + n] : -INFINITY;
        m = fmaxf(m, sv[i]);
    }
#pragma unroll
    for (int o = 32; o; o >>= 1) m = fmaxf(m, __shfl_xor(m, o));
    int w = t >> 6, lane = t & 63;
    if (lane == 0) red[w] = m;
    __syncthreads();
    m = fmaxf(fmaxf(red[0], red[1]), fmaxf(red[2], red[3]));
    float s = 0.f;
#pragma unroll
    for (int i = 0; i < 4; ++i) {
        int n = t + 256 * i;
        sv[i] = (n < NNODES) ? expf(sv[i] - m) : 0.f;
        s += sv[i];
    }
#pragma unroll
    for (int o = 32; o; o >>= 1) s += __shfl_xor(s, o);
    __syncthreads();
    if (lane == 0) red[w] = s;
    __syncthreads();
    s = red[0] + red[1] + red[2] + red[3];
    float inv = 1.0f / s;
#pragma unroll
    for (int i = 0; i < 4; ++i) {
        int n = t + 256 * i;
        if (n < NNODES) attn[(size_t)b * NNODES + n] = sv[i] * inv;
    }
}

// ---------------------------------------------------------------------------
// context partials
// ---------------------------------------------------------------------------
__global__ void k_context(const ushort_t* __restrict__ hhi, const ushort_t* __restrict__ hlo,
                          const float* __restrict__ attn, float* __restrict__ partial)
{
    int b = blockIdx.x, ch = blockIdx.y, k = threadIdx.x;
    int n0 = ch * 128;
    int n1 = n0 + 128; if (n1 > NNODES) n1 = NNODES;
    float s = 0.f;
    for (int n = n0; n < n1; ++n) {
        size_t i = ((size_t)b * NNODES + n) * HD + k;
        s = fmaf(attn[(size_t)b * NNODES + n], rh2(hhi[i], hlo[i]), s);
    }
    partial[((size_t)b * 8 + ch) * HD + k] = s;
}

// ---------------------------------------------------------------------------
// final head
// ---------------------------------------------------------------------------
__global__ void k_final(const float* __restrict__ partial,
                        const float* __restrict__ wh_W, const float* __restrict__ wh_b,
                        const float* __restrict__ lin_W, const float* __restrict__ lin_b,
                        float* __restrict__ out)
{
    int b = blockIdx.x, j = threadIdx.x;
    __shared__ float ctx[HD];
    __shared__ float hid[HD];
    float s = 0.f;
#pragma unroll
    for (int ch = 0; ch < 8; ++ch) s += partial[((size_t)b * 8 + ch) * HD + j];
    ctx[j] = s;
    __syncthreads();
    float a = wh_b[j];
    for (int k = 0; k < HD; ++k) a = fmaf(ctx[k], wh_W[j * HD + k], a);
    hid[j] = fmaxf(a, 0.f);
    __syncthreads();
    if (j < 10) {
        float o = lin_b[j];
        for (int k = 0; k < HD; ++k) o = fmaf(hid[k], lin_W[j * HD + k], o);
        out[b * 10 + j] = o;
    }
}

// ---------------------------------------------------------------------------
extern "C" void kernel_launch(void* const* d_in, const int* in_sizes, int n_in,
                              void* d_out, int out_size, void* d_ws, size_t ws_size,
                              hipStream_t stream)
{
    const int*   wordid = (const int*)d_in[0];
    const float* c0     = (const float*)d_in[2];
    const float* emb    = (const float*)d_in[3];
    const float* W_iou  = (const float*)d_in[4];
    const float* U_iou  = (const float*)d_in[5];
    const float* b_iou  = (const float*)d_in[6];
    const float* Uf_W   = (const float*)d_in[7];
    const float* Uf_b   = (const float*)d_in[8];
    const float* Wmem   = (const float*)d_in[9];
    const float* wh_W   = (const float*)d_in[10];
    const float* wh_b   = (const float*)d_in[11];
    const float* lin_W  = (const float*)d_in[12];
    const float* lin_b  = (const float*)d_in[13];
    float* out = (float*)d_out;

    const int V = in_sizes[3] / 256;     // vocab (32000)
    const size_t nh = (size_t)BB * NNODES * HD;

    char* ws = (char*)d_ws;
    size_t off = 0;
    auto alloc = [&](size_t bytes) -> void* {
        void* p = ws + off;
        off += (bytes + 255) & ~(size_t)255;
        return p;
    };
    ushort_t* hhi  = (ushort_t*)alloc(nh * 2);
    ushort_t* hlo  = (ushort_t*)alloc(nh * 2);
    float*    c    = (float*)   alloc(nh * 4);
    ushort_t* ehi  = (ushort_t*)alloc((size_t)V * 256 * 2);
    ushort_t* elo  = (ushort_t*)alloc((size_t)V * 256 * 2);
    ushort_t* wchi = (ushort_t*)alloc((size_t)LDCOMB * 512 * 2);
    ushort_t* wclo = (ushort_t*)alloc((size_t)LDCOMB * 512 * 2);
    ushort_t* wihi = (ushort_t*)alloc((size_t)IOU3 * 256 * 2);
    ushort_t* wilo = (ushort_t*)alloc((size_t)IOU3 * 256 * 2);
    int*   ids     = (int*)  alloc((size_t)BB * LEAVES * 4);
    float* v       = (float*)alloc((size_t)BB * HD * 4);
    float* scores  = (float*)alloc((size_t)BB * NNODES * 4);
    float* attn    = (float*)alloc((size_t)BB * NNODES * 4);
    float* partial = (float*)alloc((size_t)BB * 8 * HD * 4);

    size_t remain = (ws_size > off) ? (ws_size - off) : 0;
    size_t rows = remain / (LDCOMB * 4);
    int CH = (int)((rows > 32768) ? 32768 : rows);
    CH &= ~127;
    if (CH < 128) CH = 128;
    float* buf = (float*)alloc((size_t)CH * LDCOMB * 4);

    // ---- one-time splits ----
    k_split4<<<(V * 256 / 4 + 255) / 256, 256, 0, stream>>>(emb, ehi, elo, V * 256 / 4);
    k_build_wcat<<<(1280 * 128 + 255) / 256, 256, 0, stream>>>(Uf_W, U_iou, wchi, wclo);
    k_split4<<<(IOU3 * 256 / 4 + 255) / 256, 256, 0, stream>>>(W_iou, wihi, wilo, IOU3 * 256 / 4);
    k_leaf_ids<<<(BB * LEAVES) / 256, 256, 0, stream>>>(wordid, ids);

    // ---- leaves: gather GEMM (K=256, N=768) + apply ----
    {
        int M = BB * LEAVES;
        for (int m0 = 0; m0 < M; m0 += CH) {
            int Mc = M - m0; if (Mc > CH) Mc = CH;
            dim3 g(Mc / BM, IOU3 / BN);
            gemm_mfma<<<g, 256, 0, stream>>>(ehi, elo, ids, 0, 0u, 0, m0, 256,
                                             wihi, wilo, buf, IOU3);
            k_apply_leaf<<<Mc, 256, 0, stream>>>(buf, b_iou, c0, hhi, hlo, c, m0);
        }
    }

    // ---- internal levels, deepest first: fused [Uf;U_iou] GEMM (K=512,N=1280) ----
    for (int L = 8; L >= 0; --L) {
        int npar = 1 << L;
        int ps = (1 << L) - 1;
        int cs = (1 << (L + 1)) - 1;
        int M = BB * npar;
        unsigned sB = NNODES * HD;          // batch stride in h (elements)
        int sP = 2 * HD;                    // parent stride (children contiguous)
        const ushort_t* Abh = hhi + (size_t)cs * HD;
        const ushort_t* Abl = hlo + (size_t)cs * HD;
        for (int m0 = 0; m0 < M; m0 += CH) {
            int Mc = M - m0; if (Mc > CH) Mc = CH;
            dim3 g(Mc / BM, LDCOMB / BN);
            gemm_mfma<<<g, 256, 0, stream>>>(Abh, Abl, (const int*)nullptr, L, sB, sP,
                                             m0, CAT2, wchi, wclo, buf, LDCOMB);
            k_apply_level<<<Mc, 256, 0, stream>>>(buf, b_iou, Uf_b, hhi, hlo, c,
                                                  m0, L, ps, cs);
        }
    }

    // ---- attention + head ----
    k_dec_v<<<BB, HD, 0, stream>>>(hhi, hlo, Wmem, v);
    k_scores<<<dim3(BB, 256), 256, 0, stream>>>(hhi, hlo, v, scores);
    k_softmax<<<BB, 256, 0, stream>>>(scores, attn);
    k_context<<<dim3(BB, 8), HD, 0, stream>>>(hhi, hlo, attn, partial);
    k_final<<<BB, HD, 0, stream>>>(partial, wh_W, wh_b, lin_W, lin_b, out);
}

// Round 11
// 740.984 us; speedup vs baseline: 1.2049x; 1.2049x over previous
//
#include <hip/hip_runtime.h>
#include <math.h>

// Problem constants
#define BB      128
#define NNODES  1023
#define HD      256
#define LEAVES  512
#define IOU3    768     // 3*H
#define CAT2    512     // 2*H
#define LDCOMB  1280    // f(512) + iou(768)

typedef unsigned short ushort_t;
typedef __bf16 bf16x8 __attribute__((ext_vector_type(8)));
typedef float  f32x4  __attribute__((ext_vector_type(4)));

__device__ __forceinline__ float sigf(float x) { return 1.0f / (1.0f + expf(-x)); }

// async global->LDS DMA, 16B per lane, linear dest (wave-uniform base + lane*16)
__device__ __forceinline__ void gload16(const void* g, void* l)
{
    __builtin_amdgcn_global_load_lds(
        (const __attribute__((address_space(1))) unsigned int*)g,
        (__attribute__((address_space(3))) unsigned int*)l, 16, 0, 0);
}

// split fp32 -> bf16 hi + bf16 lo (round-to-nearest-even, bit ops)
__device__ __forceinline__ void split_bf16(float x, ushort_t& h, ushort_t& l)
{
    unsigned u = __float_as_uint(x);
    unsigned r = u + 0x7fff + ((u >> 16) & 1);
    h = (ushort_t)(r >> 16);
    float fh = __uint_as_float((unsigned)h << 16);
    float d = x - fh;
    unsigned u2 = __float_as_uint(d);
    unsigned r2 = u2 + 0x7fff + ((u2 >> 16) & 1);
    l = (ushort_t)(r2 >> 16);
}

__device__ __forceinline__ float rh2(ushort_t h, ushort_t l)
{
    return __uint_as_float((unsigned)h << 16) + __uint_as_float((unsigned)l << 16);
}

// ---------------------------------------------------------------------------
// generic fp32 array -> hi/lo bf16 arrays (4 elements/thread)
// ---------------------------------------------------------------------------
__global__ void k_split4(const float* __restrict__ src, ushort_t* __restrict__ hi,
                         ushort_t* __restrict__ lo, int n4)
{
    int i = blockIdx.x * 256 + threadIdx.x;
    if (i >= n4) return;
    float4 v = ((const float4*)src)[i];
    ushort4 hv, lv;
    split_bf16(v.x, hv.x, lv.x);
    split_bf16(v.y, hv.y, lv.y);
    split_bf16(v.z, hv.z, lv.z);
    split_bf16(v.w, hv.w, lv.w);
    ((ushort4*)hi)[i] = hv;
    ((ushort4*)lo)[i] = lv;
}

// build Wcat = [Uf_W(512 rows) ; U_iou(768 rows)], K=512, as hi/lo bf16
__global__ void k_build_wcat(const float* __restrict__ Uf, const float* __restrict__ Ui,
                             ushort_t* __restrict__ hi, ushort_t* __restrict__ lo)
{
    int i = blockIdx.x * 256 + threadIdx.x;       // over 1280*128 float4s
    if (i >= 1280 * 128) return;
    int row = i >> 7, c4 = i & 127;
    const float* src = (row < 512) ? (Uf + (size_t)row * 512)
                                   : (Ui + (size_t)(row - 512) * 512);
    float4 v = ((const float4*)src)[c4];
    ushort4 hv, lv;
    split_bf16(v.x, hv.x, lv.x);
    split_bf16(v.y, hv.y, lv.y);
    split_bf16(v.z, hv.z, lv.z);
    split_bf16(v.w, hv.w, lv.w);
    ((ushort4*)hi)[i] = hv;
    ((ushort4*)lo)[i] = lv;
}

// ---------------------------------------------------------------------------
// MFMA split-bf16 GEMM:  C[m][n] = sum_k A[m][k]*W[n][k]  (fp32-accurate)
// Block 128x128, BK=32, 512 threads = 8 waves (2m x 4n), wave tile 64x32.
// PROVEN pieces only (round-9/10 lesson: don't invent new LDS layouts):
//  - read pattern + 4-slot XOR swizzle from round 5 (conflicts ~0)
//  - DMA source-swizzled staging + counted-vmcnt pipeline from rounds 7/8
//  - 64KB dbuf -> 2 blocks/CU x 8 waves = 16 waves/CU (round-5 occupancy,
//    round-8's in-flight loads across barriers)
// Slab swizzle keeps per-XCD set < 4MB L2 (rounds 3/6 lesson: per-XCD
// A-panel set small; never a contiguous by-band per XCD).
// ---------------------------------------------------------------------------
#define BM 128
#define BN 128
#define BK 32

__global__ __launch_bounds__(512, 4)
void gemm_mfma(const ushort_t* __restrict__ Ahi, const ushort_t* __restrict__ Alo,
               const int* __restrict__ ids,
               int lognpar, unsigned sB, int sP, int m0, int K,
               const ushort_t* __restrict__ Bhi, const ushort_t* __restrict__ Blo,
               float* __restrict__ C, int ldc)
{
    __shared__ __align__(16) char lds[65536];
    const int tid = threadIdx.x;

    // slab-ordered, XCD-preserving block swizzle
    int bx = blockIdx.x, by = blockIdx.y;
    {
        const int gx = gridDim.x, gy = gridDim.y;
        if ((gx & 7) == 0) {
            int f = by * gx + bx;        // HW dispatch order (x fastest)
            int span = gy << 3;          // 8 * gy blocks per slab
            int s = f / span;
            int wv = f - s * span;
            bx = (s << 3) + (wv & 7);    // bx % 8 == f % 8 -> same XCD
            by = wv >> 3;
        }
    }

    const int w = tid >> 6, lane = tid & 63;

    // ---- DMA staging: thread t owns 16B slot t of each 8KB component.
    // slot t -> (row = t>>2, ko = t&3); source slot' = ko ^ ((row>>1)&3)
    // (inverse-swizzled source, linear LDS dest; rule #21, proven r7/r8).
    unsigned aoff, boff;
    {
        int row = tid >> 2;
        int slotp = (tid & 3) ^ ((row >> 1) & 3);
        int mg = m0 + bx * BM + row;
        unsigned ab;
        if (ids) {
            ab = (unsigned)ids[mg] * (unsigned)K;
        } else {
            int b = mg >> lognpar;
            int q = mg & ((1 << lognpar) - 1);
            ab = (unsigned)b * sB + (unsigned)q * (unsigned)sP;
        }
        aoff = ab + slotp * 8;
        boff = (unsigned)(by * BN + row) * (unsigned)K + slotp * 8;
    }
    const int wdst = w * 1024;                     // wave-uniform dest offset

    auto STAGE = [&](int k0, char* buf) {
        gload16(Ahi + aoff + k0, buf +     0 + wdst);
        gload16(Alo + aoff + k0, buf +  8192 + wdst);
        gload16(Bhi + boff + k0, buf + 16384 + wdst);
        gload16(Blo + boff + k0, buf + 24576 + wdst);
    };

    // fragment read addresses (round-5 proven): 8 waves as 2(m) x 4(n);
    // wave tile 64x32.
    const int wm = w >> 2, wn = w & 3;
    const int rA0 = wm * 64 + (lane & 15);
    const int rB0 = wn * 32 + (lane & 15);
    const int ko = lane >> 4;
    const int rdA = rA0 * 64 + ((ko ^ ((rA0 >> 1) & 3)) << 4);
    const int rdB = rB0 * 64 + ((ko ^ ((rB0 >> 1) & 3)) << 4);

    f32x4 acc[4][2];
#pragma unroll
    for (int mi = 0; mi < 4; ++mi)
#pragma unroll
        for (int ni = 0; ni < 2; ++ni) acc[mi][ni] = (f32x4){0.f, 0.f, 0.f, 0.f};

    const int nt = K / BK;
    STAGE(0, lds);
    int cur = 0;
    for (int t = 0; t < nt; ++t) {
        if (t + 1 < nt) {
            STAGE((t + 1) * BK, lds + (cur ^ 1) * 32768);
            asm volatile("s_waitcnt vmcnt(4)" ::: "memory");   // stage-t landed
        } else {
            asm volatile("s_waitcnt vmcnt(0)" ::: "memory");   // final drain
        }
        __builtin_amdgcn_s_barrier();          // all waves: buf[cur] ready
        __builtin_amdgcn_sched_barrier(0);
        char* base = lds + cur * 32768;
        bf16x8 ah[4], al[4], bh[2], bl[2];
#pragma unroll
        for (int f = 0; f < 4; ++f) {
            ah[f] = *(const bf16x8*)(base +        rdA + f * 1024);
            al[f] = *(const bf16x8*)(base + 8192 + rdA + f * 1024);
        }
#pragma unroll
        for (int f = 0; f < 2; ++f) {
            bh[f] = *(const bf16x8*)(base + 16384 + rdB + f * 1024);
            bl[f] = *(const bf16x8*)(base + 24576 + rdB + f * 1024);
        }
        __builtin_amdgcn_s_setprio(1);
#pragma unroll
        for (int mi = 0; mi < 4; ++mi)
#pragma unroll
            for (int ni = 0; ni < 2; ++ni) {
                acc[mi][ni] = __builtin_amdgcn_mfma_f32_16x16x32_bf16(ah[mi], bh[ni], acc[mi][ni], 0, 0, 0);
                acc[mi][ni] = __builtin_amdgcn_mfma_f32_16x16x32_bf16(ah[mi], bl[ni], acc[mi][ni], 0, 0, 0);
                acc[mi][ni] = __builtin_amdgcn_mfma_f32_16x16x32_bf16(al[mi], bh[ni], acc[mi][ni], 0, 0, 0);
            }
        __builtin_amdgcn_s_setprio(0);
        __builtin_amdgcn_s_barrier();          // reads of buf[cur] done
        cur ^= 1;
    }

    // ---- epilogue (round-5 proven): per-wave repack -> 128B bursts ----
    // wave w uses lds[w*2304 .. +2304): 16 rows x 144B (32 floats + 4 pad)
    {
        char* patch = lds + w * 2304;
        const int cl = lane & 15, rg = lane >> 4;
        const int gcol0 = by * BN + wn * 32;
#pragma unroll
        for (int mi = 0; mi < 4; ++mi) {
#pragma unroll
            for (int ni = 0; ni < 2; ++ni)
#pragma unroll
                for (int r = 0; r < 4; ++r)
                    *(float*)(patch + (rg * 4 + r) * 144 + (ni * 16 + cl) * 4) = acc[mi][ni][r];
            int grow0 = bx * BM + wm * 64 + mi * 16;
#pragma unroll
            for (int i = 0; i < 2; ++i) {
                int slot = lane + 64 * i;
                int lr = slot >> 3, c4 = slot & 7;
                f32x4 vv = *(const f32x4*)(patch + lr * 144 + c4 * 16);
                *(f32x4*)(C + (size_t)(grow0 + lr) * ldc + gcol0 + c4 * 4) = vv;
            }
        }
    }
}

// ---------------------------------------------------------------------------
// leaf id gather
// ---------------------------------------------------------------------------
__global__ void k_leaf_ids(const int* __restrict__ wordid, int* __restrict__ ids)
{
    int idx = blockIdx.x * 256 + threadIdx.x;   // 65536 total
    int b = idx >> 9, leaf = idx & 511;
    ids[idx] = wordid[b * NNODES + 511 + leaf];
}

// ---------------------------------------------------------------------------
// leaf apply: buf[m][768] (iou) -> h(hi/lo), c at node 511+leaf
// ---------------------------------------------------------------------------
__global__ void k_apply_leaf(const float* __restrict__ buf, const float* __restrict__ b_iou,
                             const float* __restrict__ c0,
                             ushort_t* __restrict__ hhi, ushort_t* __restrict__ hlo,
                             float* __restrict__ c, int m0)
{
    int idx = blockIdx.x * 256 + threadIdx.x;
    int m_l = idx >> 8, hh = idx & 255;
    int mg = m0 + m_l;
    int b = mg >> 9, leaf = mg & 511;
    int node = 511 + leaf;
    const float* br = buf + (size_t)m_l * IOU3;
    float iv = br[hh]        + b_iou[hh];
    float ov = br[256 + hh]  + b_iou[256 + hh];
    float uv = br[512 + hh]  + b_iou[512 + hh];
    size_t nb = ((size_t)b * NNODES + node) * HD + hh;
    float cn = sigf(iv) * tanhf(uv) + c0[nb];
    float hn = sigf(ov) * tanhf(cn);
    c[nb] = cn;
    split_bf16(hn, hhi[nb], hlo[nb]);
}

// ---------------------------------------------------------------------------
// level apply: buf[m][1280] = [f_l | f_r | i | o | u]
// ---------------------------------------------------------------------------
__global__ void k_apply_level(const float* __restrict__ buf, const float* __restrict__ b_iou,
                              const float* __restrict__ Uf_b,
                              ushort_t* __restrict__ hhi, ushort_t* __restrict__ hlo,
                              float* __restrict__ c,
                              int m0, int lognpar, int ps, int cs)
{
    int idx = blockIdx.x * 256 + threadIdx.x;
    int m_l = idx >> 8, hh = idx & 255;
    int mg = m0 + m_l;
    int b = mg >> lognpar;
    int p = mg & ((1 << lognpar) - 1);
    const float* br = buf + (size_t)m_l * LDCOMB;
    float fl = sigf(br[hh]        + Uf_b[hh]);
    float fr = sigf(br[256 + hh]  + Uf_b[256 + hh]);
    size_t cb = ((size_t)b * NNODES + cs + 2 * p) * HD + hh;
    float csum = fl * c[cb] + fr * c[cb + HD];
    float iv = br[512 + hh]  + b_iou[hh];
    float ov = br[768 + hh]  + b_iou[256 + hh];
    float uv = br[1024 + hh] + b_iou[512 + hh];
    float cn = sigf(iv) * tanhf(uv) + csum;
    float hn = sigf(ov) * tanhf(cn);
    size_t pb = ((size_t)b * NNODES + ps + p) * HD + hh;
    c[pb] = cn;
    split_bf16(hn, hhi[pb], hlo[pb]);
}

// ---------------------------------------------------------------------------
// v[b][k] = sum_g h[b][0][g] * Wmem[g][k]
// ---------------------------------------------------------------------------
__global__ void k_dec_v(const ushort_t* __restrict__ hhi, const ushort_t* __restrict__ hlo,
                        const float* __restrict__ Wmem, float* __restrict__ v)
{
    int b = blockIdx.x, k = threadIdx.x;
    __shared__ float dec[HD];
    size_t base = (size_t)b * NNODES * HD;
    dec[k] = rh2(hhi[base + k], hlo[base + k]);
    __syncthreads();
    float s = 0.f;
    for (int g = 0; g < HD; ++g) s = fmaf(dec[g], Wmem[g * HD + k], s);
    v[b * HD + k] = s;
}

// ---------------------------------------------------------------------------
// scores[b][n] = v_b . h[b][n]
// ---------------------------------------------------------------------------
__global__ void k_scores(const ushort_t* __restrict__ hhi, const ushort_t* __restrict__ hlo,
                         const float* __restrict__ v, float* __restrict__ scores)
{
    int b = blockIdx.x;
    int w = threadIdx.x >> 6, lane = threadIdx.x & 63;
    int n = blockIdx.y * 4 + w;
    if (n >= NNODES) return;
    size_t hb = ((size_t)b * NNODES + n) * HD;
    ushort4 ph = *(const ushort4*)(hhi + hb + lane * 4);
    ushort4 pl = *(const ushort4*)(hlo + hb + lane * 4);
    float4 vv = *(const float4*)(v + b * HD + lane * 4);
    float s = rh2(ph.x, pl.x) * vv.x + rh2(ph.y, pl.y) * vv.y +
              rh2(ph.z, pl.z) * vv.z + rh2(ph.w, pl.w) * vv.w;
#pragma unroll
    for (int o = 32; o; o >>= 1) s += __shfl_down(s, o);
    if (lane == 0) scores[(size_t)b * NNODES + n] = s;
}

// ---------------------------------------------------------------------------
// softmax over n (1023) per batch row
// ---------------------------------------------------------------------------
__global__ void k_softmax(const float* __restrict__ scores, float* __restrict__ attn)
{
    int b = blockIdx.x, t = threadIdx.x;
    __shared__ float red[4];
    float sv[4];
    float m = -INFINITY;
#pragma unroll
    for (int i = 0; i < 4; ++i) {
        int n = t + 256 * i;
        sv[i] = (n < NNODES) ? scores[(size_t)b * NNODES + n] : -INFINITY;
        m = fmaxf(m, sv[i]);
    }
#pragma unroll
    for (int o = 32; o; o >>= 1) m = fmaxf(m, __shfl_xor(m, o));
    int w = t >> 6, lane = t & 63;
    if (lane == 0) red[w] = m;
    __syncthreads();
    m = fmaxf(fmaxf(red[0], red[1]), fmaxf(red[2], red[3]));
    float s = 0.f;
#pragma unroll
    for (int i = 0; i < 4; ++i) {
        int n = t + 256 * i;
        sv[i] = (n < NNODES) ? expf(sv[i] - m) : 0.f;
        s += sv[i];
    }
#pragma unroll
    for (int o = 32; o; o >>= 1) s += __shfl_xor(s, o);
    __syncthreads();
    if (lane == 0) red[w] = s;
    __syncthreads();
    s = red[0] + red[1] + red[2] + red[3];
    float inv = 1.0f / s;
#pragma unroll
    for (int i = 0; i < 4; ++i) {
        int n = t + 256 * i;
        if (n < NNODES) attn[(size_t)b * NNODES + n] = sv[i] * inv;
    }
}

// ---------------------------------------------------------------------------
// context partials
// ---------------------------------------------------------------------------
__global__ void k_context(const ushort_t* __restrict__ hhi, const ushort_t* __restrict__ hlo,
                          const float* __restrict__ attn, float* __restrict__ partial)
{
    int b = blockIdx.x, ch = blockIdx.y, k = threadIdx.x;
    int n0 = ch * 128;
    int n1 = n0 + 128; if (n1 > NNODES) n1 = NNODES;
    float s = 0.f;
    for (int n = n0; n < n1; ++n) {
        size_t i = ((size_t)b * NNODES + n) * HD + k;
        s = fmaf(attn[(size_t)b * NNODES + n], rh2(hhi[i], hlo[i]), s);
    }
    partial[((size_t)b * 8 + ch) * HD + k] = s;
}

// ---------------------------------------------------------------------------
// final head
// ---------------------------------------------------------------------------
__global__ void k_final(const float* __restrict__ partial,
                        const float* __restrict__ wh_W, const float* __restrict__ wh_b,
                        const float* __restrict__ lin_W, const float* __restrict__ lin_b,
                        float* __restrict__ out)
{
    int b = blockIdx.x, j = threadIdx.x;
    __shared__ float ctx[HD];
    __shared__ float hid[HD];
    float s = 0.f;
#pragma unroll
    for (int ch = 0; ch < 8; ++ch) s += partial[((size_t)b * 8 + ch) * HD + j];
    ctx[j] = s;
    __syncthreads();
    float a = wh_b[j];
    for (int k = 0; k < HD; ++k) a = fmaf(ctx[k], wh_W[j * HD + k], a);
    hid[j] = fmaxf(a, 0.f);
    __syncthreads();
    if (j < 10) {
        float o = lin_b[j];
        for (int k = 0; k < HD; ++k) o = fmaf(hid[k], lin_W[j * HD + k], o);
        out[b * 10 + j] = o;
    }
}

// ---------------------------------------------------------------------------
extern "C" void kernel_launch(void* const* d_in, const int* in_sizes, int n_in,
                              void* d_out, int out_size, void* d_ws, size_t ws_size,
                              hipStream_t stream)
{
    const int*   wordid = (const int*)d_in[0];
    const float* c0     = (const float*)d_in[2];
    const float* emb    = (const float*)d_in[3];
    const float* W_iou  = (const float*)d_in[4];
    const float* U_iou  = (const float*)d_in[5];
    const float* b_iou  = (const float*)d_in[6];
    const float* Uf_W   = (const float*)d_in[7];
    const float* Uf_b   = (const float*)d_in[8];
    const float* Wmem   = (const float*)d_in[9];
    const float* wh_W   = (const float*)d_in[10];
    const float* wh_b   = (const float*)d_in[11];
    const float* lin_W  = (const float*)d_in[12];
    const float* lin_b  = (const float*)d_in[13];
    float* out = (float*)d_out;

    const int V = in_sizes[3] / 256;     // vocab (32000)
    const size_t nh = (size_t)BB * NNODES * HD;

    char* ws = (char*)d_ws;
    size_t off = 0;
    auto alloc = [&](size_t bytes) -> void* {
        void* p = ws + off;
        off += (bytes + 255) & ~(size_t)255;
        return p;
    };
    ushort_t* hhi  = (ushort_t*)alloc(nh * 2);
    ushort_t* hlo  = (ushort_t*)alloc(nh * 2);
    float*    c    = (float*)   alloc(nh * 4);
    ushort_t* ehi  = (ushort_t*)alloc((size_t)V * 256 * 2);
    ushort_t* elo  = (ushort_t*)alloc((size_t)V * 256 * 2);
    ushort_t* wchi = (ushort_t*)alloc((size_t)LDCOMB * 512 * 2);
    ushort_t* wclo = (ushort_t*)alloc((size_t)LDCOMB * 512 * 2);
    ushort_t* wihi = (ushort_t*)alloc((size_t)IOU3 * 256 * 2);
    ushort_t* wilo = (ushort_t*)alloc((size_t)IOU3 * 256 * 2);
    int*   ids     = (int*)  alloc((size_t)BB * LEAVES * 4);
    float* v       = (float*)alloc((size_t)BB * HD * 4);
    float* scores  = (float*)alloc((size_t)BB * NNODES * 4);
    float* attn    = (float*)alloc((size_t)BB * NNODES * 4);
    float* partial = (float*)alloc((size_t)BB * 8 * HD * 4);

    size_t remain = (ws_size > off) ? (ws_size - off) : 0;
    size_t rows = remain / (LDCOMB * 4);
    int CH = (int)((rows > 32768) ? 32768 : rows);
    CH &= ~127;
    if (CH < 128) CH = 128;
    float* buf = (float*)alloc((size_t)CH * LDCOMB * 4);

    // ---- one-time splits ----
    k_split4<<<(V * 256 / 4 + 255) / 256, 256, 0, stream>>>(emb, ehi, elo, V * 256 / 4);
    k_build_wcat<<<(1280 * 128 + 255) / 256, 256, 0, stream>>>(Uf_W, U_iou, wchi, wclo);
    k_split4<<<(IOU3 * 256 / 4 + 255) / 256, 256, 0, stream>>>(W_iou, wihi, wilo, IOU3 * 256 / 4);
    k_leaf_ids<<<(BB * LEAVES) / 256, 256, 0, stream>>>(wordid, ids);

    // ---- leaves: gather GEMM (K=256, N=768) + apply ----
    {
        int M = BB * LEAVES;
        for (int m0 = 0; m0 < M; m0 += CH) {
            int Mc = M - m0; if (Mc > CH) Mc = CH;
            dim3 g(Mc / BM, IOU3 / BN);
            gemm_mfma<<<g, 512, 0, stream>>>(ehi, elo, ids, 0, 0u, 0, m0, 256,
                                             wihi, wilo, buf, IOU3);
            k_apply_leaf<<<Mc, 256, 0, stream>>>(buf, b_iou, c0, hhi, hlo, c, m0);
        }
    }

    // ---- internal levels, deepest first: fused [Uf;U_iou] GEMM (K=512,N=1280) ----
    for (int L = 8; L >= 0; --L) {
        int npar = 1 << L;
        int ps = (1 << L) - 1;
        int cs = (1 << (L + 1)) - 1;
        int M = BB * npar;
        unsigned sB = NNODES * HD;          // batch stride in h (elements)
        int sP = 2 * HD;                    // parent stride (children contiguous)
        const ushort_t* Abh = hhi + (size_t)cs * HD;
        const ushort_t* Abl = hlo + (size_t)cs * HD;
        for (int m0 = 0; m0 < M; m0 += CH) {
            int Mc = M - m0; if (Mc > CH) Mc = CH;
            dim3 g(Mc / BM, LDCOMB / BN);
            gemm_mfma<<<g, 512, 0, stream>>>(Abh, Abl, (const int*)nullptr, L, sB, sP,
                                             m0, CAT2, wchi, wclo, buf, LDCOMB);
            k_apply_level<<<Mc, 256, 0, stream>>>(buf, b_iou, Uf_b, hhi, hlo, c,
                                                  m0, L, ps, cs);
        }
    }

    // ---- attention + head ----
    k_dec_v<<<BB, HD, 0, stream>>>(hhi, hlo, Wmem, v);
    k_scores<<<dim3(BB, 256), 256, 0, stream>>>(hhi, hlo, v, scores);
    k_softmax<<<BB, 256, 0, stream>>>(scores, attn);
    k_context<<<dim3(BB, 8), HD, 0, stream>>>(hhi, hlo, attn, partial);
    k_final<<<BB, HD, 0, stream>>>(partial, wh_W, wh_b, lin_W, lin_b, out);
}